// Round 7
// baseline (69.927 us; speedup 1.0000x reference)
//
#include <hip/hip_runtime.h>
#include <hip/hip_bf16.h>

#define NROWS 8192
#define DIM   128
#define NT    64                  // NROWS / 128 tiles per dim
#define NBLK  (NT * (NT + 1) / 2) // 2080 triangle tiles (8 * 260)
#define TOTAL_OUT 33550336u       // NROWS*(NROWS-1)/2

typedef short bf16x8 __attribute__((ext_vector_type(8)));
typedef float f32x4  __attribute__((ext_vector_type(4)));
typedef unsigned short u16x8 __attribute__((ext_vector_type(8)));

// fp32 -> bf16 round-to-nearest-even
static __device__ inline unsigned short f32_to_bf16(float f) {
    unsigned int u = __float_as_uint(f);
    u += 0x7FFFu + ((u >> 16) & 1u);
    return (unsigned short)(u >> 16);
}

// swizzled LDS word index for the [64 u][128 l] f32 transpose buffer:
// 16B chunks XOR'd by (row&7) -> write b128s spread across bank groups,
// row base = row*512B stays 16B-aligned.
static __device__ inline int tidx(int row, int col) {
    return row * 128 + ((((col >> 2) ^ (row & 7)) << 2) | (col & 3));
}

// Block = one 16-row group. bf16 convert + FRAGMENT-MAJOR layout:
//   Xr[((g*4 + kk)*64 + lane)*8] : row g*16+(lane&15), cols ((kk*4+(lane>>4))*8 ..+8)
// Each MFMA fragment load in pdist = one contiguous 1KB wave load. Also fp32 norms.
__global__ __launch_bounds__(256) void prep_kernel(const float* __restrict__ X,
                                                   unsigned short* __restrict__ Xr,
                                                   float* __restrict__ sq,
                                                   float* __restrict__ out) {
    __shared__ float sm[16][17];
    const int g = blockIdx.x;
    const int t = threadIdx.x;
    const int kk = t >> 6, lane = t & 63;
    const int lrow = lane & 15, kgrp = lane >> 4;

    const float* src = X + (size_t)(g * 16 + lrow) * DIM + (kk * 4 + kgrp) * 8;
    const float4 v0 = *reinterpret_cast<const float4*>(src);
    const float4 v1 = *reinterpret_cast<const float4*>(src + 4);

    u16x8 h;
    h[0] = f32_to_bf16(v0.x); h[1] = f32_to_bf16(v0.y);
    h[2] = f32_to_bf16(v0.z); h[3] = f32_to_bf16(v0.w);
    h[4] = f32_to_bf16(v1.x); h[5] = f32_to_bf16(v1.y);
    h[6] = f32_to_bf16(v1.z); h[7] = f32_to_bf16(v1.w);
    *reinterpret_cast<u16x8*>(Xr + ((size_t)(g * 4 + kk) * 64 + lane) * 8) = h;

    float p = v0.x * v0.x + v0.y * v0.y + v0.z * v0.z + v0.w * v0.w
            + v1.x * v1.x + v1.y * v1.y + v1.z * v1.z + v1.w * v1.w;
    sm[lrow][kk * 4 + kgrp] = p;
    __syncthreads();
    if (t < 16) {
        float s = 0.f;
        #pragma unroll
        for (int j = 0; j < 16; ++j) s += sm[t][j];
        sq[g * 16 + t] = s;
    }
    if (g == 0 && t == 0) out[TOTAL_OUT - 1] = 0.0f; // skipped pair (0,1) slot
}

// 128x128 triangle tile, 4 waves (2x2), no staging LDS (L2-resident frag-major
// loads). Epilogue: two-pass LDS transpose -> per-u-row 512B runs stored with
// 16B-ALIGNED dwordx4 body + scalar head/tail (kills sector-straddle
// amplification of 4B-aligned stores). XCD-chunked block swizzle (bijective).
__global__ __launch_bounds__(256) void pdist_kernel(const unsigned short* __restrict__ Xr,
                                                    const float* __restrict__ sq,
                                                    float* __restrict__ out) {
    __shared__ float smT[64 * 128];   // 32 KB transpose buffer (one u-half)

    const int t    = threadIdx.x;
    const int phys = blockIdx.x;
    const int bt   = (phys & 7) * (NBLK / 8) + (phys >> 3);
    // decode triangle index: bt = bj*(bj+1)/2 + bi, bi <= bj
    int bj = (int)((sqrtf(8.0f * (float)bt + 1.0f) - 1.0f) * 0.5f);
    while ((bj + 1) * (bj + 2) / 2 <= bt) ++bj;
    while (bj * (bj + 1) / 2 > bt) --bj;
    const int bi = bt - bj * (bj + 1) / 2;

    const int wid  = t >> 6;
    const int lane = t & 63;
    const int wr   = wid >> 1;   // wave row (l dim), 0..1
    const int wc   = wid & 1;    // wave col (u dim), 0..1
    const int lrow = lane & 15;
    const int kgrp = lane >> 4;

    const bf16x8* __restrict__ F = reinterpret_cast<const bf16x8*>(Xr);
    const int gA = bi * 8 + wr * 4;
    const int gB = bj * 8 + wc * 4;

    f32x4 acc[4][4];
    const f32x4 fzero = {0.f, 0.f, 0.f, 0.f};
    #pragma unroll
    for (int m = 0; m < 4; ++m)
        #pragma unroll
        for (int n = 0; n < 4; ++n) acc[m][n] = fzero;

    bf16x8 a[2][4], b[2][4];
    #pragma unroll
    for (int m = 0; m < 4; ++m) {
        a[0][m] = F[((gA + m) * 4 + 0) * 64 + lane];
        b[0][m] = F[((gB + m) * 4 + 0) * 64 + lane];
    }
    #pragma unroll
    for (int kk = 0; kk < 4; ++kk) {
        const int cur = kk & 1, nxt = cur ^ 1;
        if (kk < 3) {
            #pragma unroll
            for (int m = 0; m < 4; ++m) {
                a[nxt][m] = F[((gA + m) * 4 + kk + 1) * 64 + lane];
                b[nxt][m] = F[((gB + m) * 4 + kk + 1) * 64 + lane];
            }
        }
        #pragma unroll
        for (int m = 0; m < 4; ++m)
            #pragma unroll
            for (int n = 0; n < 4; ++n)
                acc[m][n] = __builtin_amdgcn_mfma_f32_16x16x32_bf16(a[cur][m], b[cur][n], acc[m][n], 0, 0, 0);
    }

    // fragment coords: u = u0 + n*16 + lrow (col), l = l0 + m*16 + kgrp*4 + j (row)
    const int l0 = bi * 128 + wr * 64;
    const int u0 = bj * 128 + wc * 64;
    const int l0blk = bi * 128;

    float squ[4];
    f32x4 sql[4];
    #pragma unroll
    for (int n = 0; n < 4; ++n) squ[n] = sq[u0 + n * 16 + lrow];
    #pragma unroll
    for (int m = 0; m < 4; ++m)
        sql[m] = *reinterpret_cast<const f32x4*>(sq + l0 + m * 16 + kgrp * 4);

    #pragma unroll
    for (int h = 0; h < 2; ++h) {        // u-halves: [bj*128 + h*64, +64)
        if (h) __syncthreads();
        if (wc == h) {                   // 2 waves own this u-half
            #pragma unroll
            for (int m = 0; m < 4; ++m) {
                #pragma unroll
                for (int n = 0; n < 4; ++n) {
                    const int u_loc = n * 16 + lrow;
                    const int l_loc = wr * 64 + m * 16 + kgrp * 4;
                    f32x4 d;
                    #pragma unroll
                    for (int j = 0; j < 4; ++j) d[j] = sql[m][j] + squ[n] - 2.0f * acc[m][n][j];
                    *reinterpret_cast<f32x4*>(&smT[tidx(u_loc, l_loc)]) = d;
                }
            }
        }
        __syncthreads();
        // store: row u_loc = t>>2, quarter q = t&3; 16B-aligned body
        {
            const int u_loc = t >> 2;
            const int q = t & 3;
            const int u = bj * 128 + h * 64 + u_loc;
            if (u >= 2) {
                int len = (bi != bj) ? 128 : (u - l0blk);
                if (len > 128) len = 128;
                if (len > 0) {
                    const size_t B = (size_t)u * (size_t)(u - 1) / 2 - 1 + (size_t)l0blk;
                    int h0 = (int)((4 - (B & 3)) & 3);
                    if (h0 > len) h0 = len;
                    const int body4 = (len - h0) >> 2;
                    if (q == 0)
                        for (int e = 0; e < h0; ++e) out[B + e] = smT[tidx(u_loc, e)];
                    const int cend = ((q + 1) * 8 < body4) ? (q + 1) * 8 : body4;
                    for (int c = q * 8; c < cend; ++c) {
                        const int col = h0 + c * 4;
                        f32x4 v;
                        #pragma unroll
                        for (int e = 0; e < 4; ++e) v[e] = smT[tidx(u_loc, col + e)];
                        __builtin_memcpy(out + B + col, &v, 16);   // 16B-aligned
                    }
                    if (q == 3)
                        for (int e = h0 + body4 * 4; e < len; ++e) out[B + e] = smT[tidx(u_loc, e)];
                }
            }
        }
    }
}

extern "C" void kernel_launch(void* const* d_in, const int* in_sizes, int n_in,
                              void* d_out, int out_size, void* d_ws, size_t ws_size,
                              hipStream_t stream) {
    const float* X = (const float*)d_in[0];
    float* out = (float*)d_out;
    unsigned short* Xr = (unsigned short*)d_ws;                       // 2 MB bf16, fragment-major
    float* sq = (float*)((char*)d_ws + (size_t)NROWS * DIM * 2);      // 32 KB norms

    prep_kernel<<<NROWS / 16, 256, 0, stream>>>(X, Xr, sq, out);
    pdist_kernel<<<NBLK, 256, 0, stream>>>(Xr, sq, out);
}